// Round 1
// baseline (241.135 us; speedup 1.0000x reference)
//
#include <hip/hip_runtime.h>
#include <hip/hip_bf16.h>

typedef unsigned short u16;
typedef unsigned int u32;
typedef __attribute__((ext_vector_type(8))) short short8;
typedef __attribute__((ext_vector_type(4))) float f32x4;

// Round-to-nearest-even f32 -> bf16 bit pattern.
__device__ __forceinline__ u16 f2bf(float f) {
    union { float f; u32 u; } c; c.f = f;
    u32 x = c.u;
    return (u16)((x + 0x7fffu + ((x >> 16) & 1u)) >> 16);
}

__global__ void cvt_kernel(const float* __restrict__ in, u16* __restrict__ out, int n4) {
    int i = blockIdx.x * blockDim.x + threadIdx.x;
    if (i >= n4) return;
    float4 v = reinterpret_cast<const float4*>(in)[i];
    ushort4 o;
    o.x = f2bf(v.x); o.y = f2bf(v.y); o.z = f2bf(v.z); o.w = f2bf(v.w);
    reinterpret_cast<ushort4*>(out)[i] = o;
}

// C(4096x1024) = A(4096x1024) * B^T, B stored row-major (1024 x 1024) = (N x K).
// MODE 0: f32 row-major to outf
// MODE 1: bf16 to (B,H,S,HD)   [Q,K layout]
// MODE 2: bf16 to (B,H,HD,S)   [V transposed layout]
template<int MODE>
__global__ __launch_bounds__(256) void gemm_nt(const u16* __restrict__ A,
                                               const u16* __restrict__ Bw,
                                               u16* __restrict__ outb,
                                               float* __restrict__ outf) {
    constexpr int K = 1024, N = 1024;
    __shared__ __align__(16) u16 Al[128][72];
    __shared__ __align__(16) u16 Bl[128][72];
    const int tid = threadIdx.x;
    const int row0 = blockIdx.y * 128, col0 = blockIdx.x * 128;
    const int wid = tid >> 6, lane = tid & 63;
    const int wr = wid >> 1, wc = wid & 1;       // 2x2 waves, each 64x64 output
    const int lr = lane & 15, lg = lane >> 4;
    const int sg = tid & 7, sr = tid >> 3;       // staging: 8 x 16B groups per 64-elem row
    f32x4 acc[4][4] = {};

    for (int kt = 0; kt < K; kt += 64) {
        #pragma unroll
        for (int it = 0; it < 4; ++it) {
            int rr = sr + it * 32;
            *reinterpret_cast<uint4*>(&Al[rr][sg * 8]) =
                *reinterpret_cast<const uint4*>(&A[(size_t)(row0 + rr) * K + kt + sg * 8]);
            *reinterpret_cast<uint4*>(&Bl[rr][sg * 8]) =
                *reinterpret_cast<const uint4*>(&Bw[(size_t)(col0 + rr) * K + kt + sg * 8]);
        }
        __syncthreads();
        #pragma unroll
        for (int ks = 0; ks < 2; ++ks) {
            short8 af[4], bfr[4];
            #pragma unroll
            for (int m = 0; m < 4; ++m)
                af[m] = *reinterpret_cast<const short8*>(&Al[wr * 64 + m * 16 + lr][ks * 32 + lg * 8]);
            #pragma unroll
            for (int n = 0; n < 4; ++n)
                bfr[n] = *reinterpret_cast<const short8*>(&Bl[wc * 64 + n * 16 + lr][ks * 32 + lg * 8]);
            #pragma unroll
            for (int m = 0; m < 4; ++m)
                #pragma unroll
                for (int n = 0; n < 4; ++n)
                    acc[m][n] = __builtin_amdgcn_mfma_f32_16x16x32_bf16(af[m], bfr[n], acc[m][n], 0, 0, 0);
        }
        __syncthreads();
    }

    #pragma unroll
    for (int m = 0; m < 4; ++m) {
        #pragma unroll
        for (int n = 0; n < 4; ++n) {
            #pragma unroll
            for (int r = 0; r < 4; ++r) {
                int gi = row0 + wr * 64 + m * 16 + lg * 4 + r;   // C/D row = (lane>>4)*4+reg
                int gj = col0 + wc * 64 + n * 16 + lr;           // C/D col = lane&15
                float v = acc[m][n][r];
                if (MODE == 0) {
                    outf[(size_t)gi * N + gj] = v;
                } else {
                    int b = gi >> 11, s = gi & 2047;
                    int h = gj >> 6, hd = gj & 63;
                    size_t idx;
                    if (MODE == 1) idx = (((size_t)(b * 16 + h) * 2048) + s) * 64 + hd;
                    else           idx = (((size_t)(b * 16 + h) * 64) + hd) * 2048 + s;
                    outb[idx] = f2bf(v);
                }
            }
        }
    }
}

// Flash attention with ALiBi + causal mask.
// Grid: x = q-block (S/64 = 32), y = b*16+h (32). 256 threads = 4 waves x 16 q-rows.
__global__ __launch_bounds__(256) void attn_kernel(const u16* __restrict__ Q,
                                                   const u16* __restrict__ Kt,
                                                   const u16* __restrict__ VT,
                                                   u16* __restrict__ attn) {
    constexpr int S = 2048, HD = 64;
    __shared__ __align__(16) u16 Ql[64][72];
    __shared__ __align__(16) u16 Kl[64][72];
    __shared__ __align__(16) u16 Vl[64][72];     // VT tile: [d][c]
    __shared__ __align__(16) u16 Pl[4][16][72];  // per-wave P for A-operand layout
    const int qb = blockIdx.x, bh = blockIdx.y;
    const int b = bh >> 4, h = bh & 15;
    const int q0 = qb * 64;
    const int tid = threadIdx.x, wid = tid >> 6, lane = tid & 63;
    const int lr = lane & 15, lg = lane >> 4;
    const float scale = 0.125f;                          // 1/sqrt(HD)
    const float slope = exp2f(-0.5f * (float)(h + 1));   // ALiBi slope for head h
    const int sg = tid & 7, sr = tid >> 3;

    const size_t qbase = ((size_t)bh * S + q0) * HD;
    #pragma unroll
    for (int it = 0; it < 2; ++it) {
        int rr = sr + it * 32;
        *reinterpret_cast<uint4*>(&Ql[rr][sg * 8]) =
            *reinterpret_cast<const uint4*>(&Q[qbase + (size_t)rr * HD + sg * 8]);
    }

    float m_run[4], l_run[4];
    f32x4 o_acc[4] = {};
    #pragma unroll
    for (int r = 0; r < 4; ++r) { m_run[r] = -1e30f; l_run[r] = 0.f; }

    const int nkv = qb + 1;                 // causal: kv blocks 0..qb
    const size_t kbase0 = (size_t)bh * S * HD;
    const size_t vbase  = (size_t)bh * HD * S;

    for (int kv = 0; kv < nkv; ++kv) {
        const int kv0 = kv * 64;
        __syncthreads();                     // prev-iter LDS reads done
        #pragma unroll
        for (int it = 0; it < 2; ++it) {
            int rr = sr + it * 32;
            *reinterpret_cast<uint4*>(&Kl[rr][sg * 8]) =
                *reinterpret_cast<const uint4*>(&Kt[kbase0 + (size_t)(kv0 + rr) * HD + sg * 8]);
            *reinterpret_cast<uint4*>(&Vl[rr][sg * 8]) =
                *reinterpret_cast<const uint4*>(&VT[vbase + (size_t)rr * S + kv0 + sg * 8]);
        }
        __syncthreads();

        // S-tile = Q K^T: wave wid handles q rows [wid*16, wid*16+16)
        f32x4 sacc[4] = {};
        #pragma unroll
        for (int ks = 0; ks < 2; ++ks) {
            short8 aq = *reinterpret_cast<const short8*>(&Ql[wid * 16 + lr][ks * 32 + lg * 8]);
            #pragma unroll
            for (int n = 0; n < 4; ++n) {
                short8 bk = *reinterpret_cast<const short8*>(&Kl[n * 16 + lr][ks * 32 + lg * 8]);
                sacc[n] = __builtin_amdgcn_mfma_f32_16x16x32_bf16(aq, bk, sacc[n], 0, 0, 0);
            }
        }

        // scale + alibi + causal mask (exact -1e6 like reference)
        float sv[4][4];
        #pragma unroll
        for (int n = 0; n < 4; ++n)
            #pragma unroll
            for (int r = 0; r < 4; ++r) {
                int gr = q0 + wid * 16 + lg * 4 + r;
                int gc = kv0 + n * 16 + lr;
                float v = sacc[n][r] * scale + slope * (float)(gc - gr);
                sv[n][r] = (gc > gr) ? -1.0e6f : v;
            }

        // online softmax per row (rows live on 16-lane groups; xor 1/2/4/8 stays in-group)
        #pragma unroll
        for (int r = 0; r < 4; ++r) {
            float mx = fmaxf(fmaxf(sv[0][r], sv[1][r]), fmaxf(sv[2][r], sv[3][r]));
            mx = fmaxf(mx, __shfl_xor(mx, 1));
            mx = fmaxf(mx, __shfl_xor(mx, 2));
            mx = fmaxf(mx, __shfl_xor(mx, 4));
            mx = fmaxf(mx, __shfl_xor(mx, 8));
            float mnew = fmaxf(m_run[r], mx);
            float ssum = 0.f;
            #pragma unroll
            for (int n = 0; n < 4; ++n) {
                float p = __expf(sv[n][r] - mnew);
                sv[n][r] = p;
                ssum += p;
            }
            ssum += __shfl_xor(ssum, 1);
            ssum += __shfl_xor(ssum, 2);
            ssum += __shfl_xor(ssum, 4);
            ssum += __shfl_xor(ssum, 8);
            float resc = __expf(m_run[r] - mnew);
            l_run[r] = l_run[r] * resc + ssum;
            m_run[r] = mnew;
            #pragma unroll
            for (int nd = 0; nd < 4; ++nd) o_acc[nd][r] *= resc;
        }

        // P -> LDS (bf16) to get A-operand layout
        #pragma unroll
        for (int n = 0; n < 4; ++n)
            #pragma unroll
            for (int r = 0; r < 4; ++r)
                Pl[wid][lg * 4 + r][n * 16 + lr] = f2bf(sv[n][r]);
        __syncthreads();

        // O += P V  (B operand from VT tile: lane reads VT[d=col][c contiguous])
        #pragma unroll
        for (int ks = 0; ks < 2; ++ks) {
            short8 ap = *reinterpret_cast<const short8*>(&Pl[wid][lr][ks * 32 + lg * 8]);
            #pragma unroll
            for (int nd = 0; nd < 4; ++nd) {
                short8 bv = *reinterpret_cast<const short8*>(&Vl[nd * 16 + lr][ks * 32 + lg * 8]);
                o_acc[nd] = __builtin_amdgcn_mfma_f32_16x16x32_bf16(ap, bv, o_acc[nd], 0, 0, 0);
            }
        }
    }

    // epilogue: O / l, write bf16 to (B,S,D) with D = h*64+hd
    #pragma unroll
    for (int r = 0; r < 4; ++r) {
        float inv = 1.f / l_run[r];
        int gs = q0 + wid * 16 + lg * 4 + r;
        size_t base = ((size_t)b * S + gs) * 1024 + h * 64;
        #pragma unroll
        for (int nd = 0; nd < 4; ++nd)
            attn[base + nd * 16 + lr] = f2bf(o_acc[nd][r] * inv);
    }
}

extern "C" void kernel_launch(void* const* d_in, const int* in_sizes, int n_in,
                              void* d_out, int out_size, void* d_ws, size_t ws_size,
                              hipStream_t stream) {
    const float* x  = (const float*)d_in[0];
    // d_in[1] is the causal mask (fixed tril) — implemented analytically.
    const float* Wq = (const float*)d_in[2];
    const float* Wk = (const float*)d_in[3];
    const float* Wv = (const float*)d_in[4];
    const float* Wo = (const float*)d_in[5];

    u16* xb  = (u16*)d_ws;            // 4096*1024
    u16* wqb = xb  + 4194304;         // 1024*1024
    u16* wkb = wqb + 1048576;
    u16* wvb = wkb + 1048576;
    u16* wob = wvb + 1048576;
    u16* Qb  = wob + 1048576;         // (B,H,S,HD)
    u16* Kb  = Qb  + 4194304;         // (B,H,S,HD)
    u16* VTb = Kb  + 4194304;         // (B,H,HD,S)
    u16* Ab  = VTb + 4194304;         // (B,S,D) bf16 attn output

    cvt_kernel<<<4096, 256, 0, stream>>>(x,  xb,  1048576);
    cvt_kernel<<<1024, 256, 0, stream>>>(Wq, wqb, 262144);
    cvt_kernel<<<1024, 256, 0, stream>>>(Wk, wkb, 262144);
    cvt_kernel<<<1024, 256, 0, stream>>>(Wv, wvb, 262144);
    cvt_kernel<<<1024, 256, 0, stream>>>(Wo, wob, 262144);

    dim3 gg(8, 32);   // N/128, M/128
    gemm_nt<1><<<gg, 256, 0, stream>>>(xb, wqb, Qb,  nullptr);
    gemm_nt<1><<<gg, 256, 0, stream>>>(xb, wkb, Kb,  nullptr);
    gemm_nt<2><<<gg, 256, 0, stream>>>(xb, wvb, VTb, nullptr);

    attn_kernel<<<dim3(32, 32), 256, 0, stream>>>(Qb, Kb, VTb, Ab);

    gemm_nt<0><<<gg, 256, 0, stream>>>(Ab, wob, nullptr, (float*)d_out);
}